// Round 1
// baseline (2890.665 us; speedup 1.0000x reference)
//
#include <hip/hip_runtime.h>

// DubinsLSTM: 2-layer LSTM (H=128) over T=200 steps, B=1024, teacher forcing.
// Persistent kernel: each block owns EPB=4 batch elements for all T steps.
// Key precompute: cond_embed @ W_ih0[3:,:] + b0 is time-invariant -> held in
// registers (cembz[e]) per column-owner thread; per-step layer-0 K shrinks
// from 259 to 131.

#define BB 1024
#define TT 200
#define INDIM 3
#define CDIM 4
#define HH 128
#define OD 3
#define GG 512   // 4*H
#define EPB 4    // batch elements per block

__device__ __forceinline__ float sigf(float x) {
    return __fdividef(1.f, 1.f + __expf(-x));
}
// safe fast tanh: 1 - 2/(e^{2x}+1); handles +-inf correctly
__device__ __forceinline__ float tanhfast(float x) {
    return 1.f - __fdividef(2.f, __expf(2.f * x) + 1.f);
}

__global__ __launch_bounds__(512, 2) void dubins_lstm_kernel(
    const float* __restrict__ conds,       // [B,4]
    const float* __restrict__ target_seq,  // [B,T,3]
    const int*   __restrict__ lengths,     // [B]
    const float* __restrict__ tf_rand,     // [T,B]
    const float* __restrict__ Wc,          // [4,128]
    const float* __restrict__ bc,          // [128]
    const float* __restrict__ Wih0,        // [131,512]
    const float* __restrict__ Whh0,        // [128,512]
    const float* __restrict__ b0,          // [512]
    const float* __restrict__ Wih1,        // [128,512]
    const float* __restrict__ Whh1,        // [128,512]
    const float* __restrict__ b1,          // [512]
    const float* __restrict__ Wo,          // [128,3]
    const float* __restrict__ bo,          // [3]
    float* __restrict__ out)               // [B,T,3]
{
    __shared__ float zb[EPB][GG];     // 8KB: gate pre-activations (reused L0/L1)
    __shared__ float h0s[EPB][HH];    // 2KB
    __shared__ float h1s[EPB][HH];    // 2KB
    __shared__ float prevs[EPB][4];   // prev autoregressive input (pad to 4)

    const int tid = threadIdx.x;
    const int b_base = blockIdx.x * EPB;
    const int j  = tid;        // gate-column owner role, j in [0,512)
    const int ge = tid >> 7;   // gate-update role: element
    const int gj = tid & 127;  // gate-update role: hidden unit

    // ---- init state ----
    h0s[ge][gj] = 0.f;
    h1s[ge][gj] = 0.f;
    if (tid < EPB * INDIM) prevs[tid / INDIM][tid % INDIM] = 0.f;

    // ---- cond_embed -> zb[e][0..127] (temp use of zb) ----
    {
        float v = bc[gj];
        #pragma unroll
        for (int k = 0; k < CDIM; ++k)
            v += conds[(b_base + ge) * CDIM + k] * Wc[k * HH + gj];
        zb[ge][gj] = v;
    }
    __syncthreads();

    // ---- time-invariant z0 part: cembz[e] = b0[j] + cemb[e,:] @ Wih0[3:,:j] ----
    float cembz[EPB];
    {
        const float bj = b0[j];
        #pragma unroll
        for (int e = 0; e < EPB; ++e) cembz[e] = bj;
        #pragma unroll 4
        for (int k = 0; k < HH; ++k) {
            const float w = Wih0[(INDIM + k) * GG + j];
            #pragma unroll
            for (int e = 0; e < EPB; ++e) cembz[e] += zb[e][k] * w;
        }
    }
    const float b1j = b1[j];

    // ---- output-phase role ----
    const int pp = tid >> 5;            // 32-lane group id
    const int pl = tid & 31;
    const int pe = pp / OD;             // element (valid if pp<12)
    const int pd = pp - pe * OD;        // out dim
    const bool predrole = (pp < EPB * OD);
    int plen = 0; float pbo = 0.f;
    if (predrole) { plen = lengths[b_base + pe]; pbo = bo[pd]; }

    float c0 = 0.f, c1 = 0.f;
    __syncthreads();   // zb temp reads done before step-0 overwrites

    for (int t = 0; t < TT; ++t) {
        float acc[EPB];

        // ========== layer-0 pre-activations ==========
        #pragma unroll
        for (int e = 0; e < EPB; ++e) acc[e] = cembz[e];
        #pragma unroll
        for (int k = 0; k < INDIM; ++k) {
            const float w = Wih0[k * GG + j];
            #pragma unroll
            for (int e = 0; e < EPB; ++e) acc[e] += prevs[e][k] * w;
        }
        {
            const float4* h4 = reinterpret_cast<const float4*>(&h0s[0][0]);
            #pragma unroll 4
            for (int kc = 0; kc < HH / 4; ++kc) {
                const float w0 = Whh0[(kc * 4 + 0) * GG + j];
                const float w1 = Whh0[(kc * 4 + 1) * GG + j];
                const float w2 = Whh0[(kc * 4 + 2) * GG + j];
                const float w3 = Whh0[(kc * 4 + 3) * GG + j];
                #pragma unroll
                for (int e = 0; e < EPB; ++e) {
                    const float4 hv = h4[e * (HH / 4) + kc];
                    acc[e] += hv.x * w0 + hv.y * w1 + hv.z * w2 + hv.w * w3;
                }
            }
        }
        #pragma unroll
        for (int e = 0; e < EPB; ++e) zb[e][j] = acc[e];
        __syncthreads();   // bar1: z0 ready

        // ========== layer-0 gate update ==========
        {
            const float zi = zb[ge][gj];
            const float zf = zb[ge][gj + HH];
            const float zg = zb[ge][gj + 2 * HH];
            const float zo = zb[ge][gj + 3 * HH];
            c0 = sigf(zf) * c0 + sigf(zi) * tanhfast(zg);
            h0s[ge][gj] = sigf(zo) * tanhfast(c0);
        }
        __syncthreads();   // bar2: h0 ready

        // ========== layer-1 pre-activations ==========
        #pragma unroll
        for (int e = 0; e < EPB; ++e) acc[e] = b1j;
        {
            const float4* h4 = reinterpret_cast<const float4*>(&h0s[0][0]);
            #pragma unroll 4
            for (int kc = 0; kc < HH / 4; ++kc) {
                const float w0 = Wih1[(kc * 4 + 0) * GG + j];
                const float w1 = Wih1[(kc * 4 + 1) * GG + j];
                const float w2 = Wih1[(kc * 4 + 2) * GG + j];
                const float w3 = Wih1[(kc * 4 + 3) * GG + j];
                #pragma unroll
                for (int e = 0; e < EPB; ++e) {
                    const float4 hv = h4[e * (HH / 4) + kc];
                    acc[e] += hv.x * w0 + hv.y * w1 + hv.z * w2 + hv.w * w3;
                }
            }
            const float4* g4 = reinterpret_cast<const float4*>(&h1s[0][0]);
            #pragma unroll 4
            for (int kc = 0; kc < HH / 4; ++kc) {
                const float w0 = Whh1[(kc * 4 + 0) * GG + j];
                const float w1 = Whh1[(kc * 4 + 1) * GG + j];
                const float w2 = Whh1[(kc * 4 + 2) * GG + j];
                const float w3 = Whh1[(kc * 4 + 3) * GG + j];
                #pragma unroll
                for (int e = 0; e < EPB; ++e) {
                    const float4 hv = g4[e * (HH / 4) + kc];
                    acc[e] += hv.x * w0 + hv.y * w1 + hv.z * w2 + hv.w * w3;
                }
            }
        }
        #pragma unroll
        for (int e = 0; e < EPB; ++e) zb[e][j] = acc[e];
        __syncthreads();   // bar3: z1 ready

        // ========== layer-1 gate update ==========
        {
            const float zi = zb[ge][gj];
            const float zf = zb[ge][gj + HH];
            const float zg = zb[ge][gj + 2 * HH];
            const float zo = zb[ge][gj + 3 * HH];
            c1 = sigf(zf) * c1 + sigf(zi) * tanhfast(zg);
            h1s[ge][gj] = sigf(zo) * tanhfast(c1);
        }
        __syncthreads();   // bar4: h1 ready

        // ========== output projection + teacher forcing ==========
        if (predrole) {
            float part = 0.f;
            #pragma unroll
            for (int kk = 0; kk < 4; ++kk) {
                const int k = pl + kk * 32;
                part += h1s[pe][k] * Wo[k * OD + pd];
            }
            part += __shfl_xor(part, 16, 32);
            part += __shfl_xor(part, 8, 32);
            part += __shfl_xor(part, 4, 32);
            part += __shfl_xor(part, 2, 32);
            part += __shfl_xor(part, 1, 32);
            if (pl == 0) {
                const float pred = part + pbo;
                const int bg = b_base + pe;
                out[(bg * TT + t) * OD + pd] = pred;
                const bool use_tf = (tf_rand[t * BB + bg] < 0.5f) && (t < plen);
                prevs[pe][pd] = use_tf ? target_seq[(bg * TT + t) * OD + pd] : pred;
            }
        }
        __syncthreads();   // bar5: prev ready for next step
    }
}

extern "C" void kernel_launch(void* const* d_in, const int* in_sizes, int n_in,
                              void* d_out, int out_size, void* d_ws, size_t ws_size,
                              hipStream_t stream) {
    const float* conds   = (const float*)d_in[0];
    const float* target  = (const float*)d_in[1];
    const int*   lengths = (const int*)d_in[2];
    const float* tfr     = (const float*)d_in[3];
    const float* Wc      = (const float*)d_in[4];
    const float* bc      = (const float*)d_in[5];
    const float* Wih0    = (const float*)d_in[6];
    const float* Whh0    = (const float*)d_in[7];
    const float* b0      = (const float*)d_in[8];
    const float* Wih1    = (const float*)d_in[9];
    const float* Whh1    = (const float*)d_in[10];
    const float* b1      = (const float*)d_in[11];
    const float* Wo      = (const float*)d_in[12];
    const float* bo      = (const float*)d_in[13];
    float* out = (float*)d_out;

    dubins_lstm_kernel<<<BB / EPB, 512, 0, stream>>>(
        conds, target, lengths, tfr, Wc, bc,
        Wih0, Whh0, b0, Wih1, Whh1, b1, Wo, bo, out);
}